// Round 5
// baseline (243.596 us; speedup 1.0000x reference)
//
#include <hip/hip_runtime.h>
#include <hip/hip_bf16.h>
#include <stdint.h>

typedef unsigned short u16;
typedef __attribute__((ext_vector_type(8))) short short8_t;
typedef __attribute__((ext_vector_type(4))) float f32x4;

#define D_DIM 512
#define K_CL  256
#define BM    32
#define NITER 16   // D_DIM / 32

__device__ __forceinline__ u16 f2bf(float f) {
  union { float f; uint32_t u; } v; v.f = f;
  uint32_t r = v.u + 0x7fffu + ((v.u >> 16) & 1u);  // RNE
  return (u16)(r >> 16);
}

// prep: clusters fp32 [256][512] -> bf16 cb [256][512] + csq[256] (fp32 norms)
__global__ void prep_kernel(const float* __restrict__ clusters,
                            u16* __restrict__ cb, float* __restrict__ csq) {
  int k = blockIdx.x;
  int t = threadIdx.x;  // 128 threads, 4 floats each
  float4 f = ((const float4*)(clusters + (size_t)k * D_DIM))[t];
  ushort4 u;
  u.x = f2bf(f.x); u.y = f2bf(f.y); u.z = f2bf(f.z); u.w = f2bf(f.w);
  ((ushort4*)(cb + (size_t)k * D_DIM))[t] = u;
  float s = f.x*f.x + f.y*f.y + f.z*f.z + f.w*f.w;
  #pragma unroll
  for (int m = 1; m < 64; m <<= 1) s += __shfl_xor(s, m, 64);
  __shared__ float part[2];
  if ((t & 63) == 0) part[t >> 6] = s;
  __syncthreads();
  if (t == 0) csq[k] = part[0] + part[1];
}

// Prologue-staged A: each block converts its ENTIRE 32x512 x-tile to bf16 LDS
// in one deep load burst (no barriers inside), so the 16-step MFMA loop has
// NO HBM dependency — only lA (LDS) + B (L2-resident workspace via
// global_load_lds). XOR bank swizzle (c ^ ((row>>1)&3)) on lA and lB.
// 256 threads = 4 waves; wave w owns cols [w*64, w*64+64) of all 32 rows.
__global__ __launch_bounds__(256, 3)
void cluster_kernel(const float* __restrict__ x,
                    const u16* __restrict__ cb,
                    const float* __restrict__ csq,
                    float* __restrict__ out) {
  __shared__ __align__(16) char lA[BM * D_DIM * 2];   // 32 KB: [slab16][row32][chunk4*16B]
  __shared__ __align__(16) char lB[K_CL * 32 * 2];    // 16 KB: [row256][chunk4*16B]
  __shared__ float csq_lds[K_CL];
  __shared__ float xsq_lds[BM];
  __shared__ float rowsum[4 * BM];                    // total ~50.4 KB -> 3 blocks/CU

  const int tid  = threadIdx.x;
  const int lane = tid & 63;
  const int w    = tid >> 6;          // wave id = column quarter
  const int quad = lane >> 4;
  const int l16  = lane & 15;
  const int row0 = blockIdx.x * BM;

  csq_lds[tid] = csq[tid];

  // ---- prologue: stage A tile (32 rows x 512 k) fp32 -> bf16 -> LDS ----
  // thread (ar = tid>>3, jc = tid&7) covers row ar, k = jc*8 + s*64, s=0..7.
  const int ar = tid >> 3;
  const int jc = tid & 7;
  const float* xg = x + (size_t)(row0 + ar) * D_DIM + jc * 8;
  const int slab0 = jc >> 2;
  const int cA = (jc & 3) ^ ((ar >> 1) & 3);          // swizzled chunk slot
  char* awbase = lA + ar * 64 + cA * 16;

  float sq = 0.f;
  #pragma unroll
  for (int g = 0; g < 2; ++g) {
    float4 f[4][2];
    #pragma unroll
    for (int s4 = 0; s4 < 4; ++s4) {                  // 8 dwordx4 in flight
      const int s = g * 4 + s4;
      f[s4][0] = *(const float4*)(xg + s * 64);
      f[s4][1] = *(const float4*)(xg + s * 64 + 4);
    }
    #pragma unroll
    for (int s4 = 0; s4 < 4; ++s4) {
      const int s = g * 4 + s4;
      float4 f0 = f[s4][0], f1 = f[s4][1];
      sq += f0.x*f0.x + f0.y*f0.y + f0.z*f0.z + f0.w*f0.w
          + f1.x*f1.x + f1.y*f1.y + f1.z*f1.z + f1.w*f1.w;
      union { u16 u[8]; short8_t v; } pk;
      pk.u[0]=f2bf(f0.x); pk.u[1]=f2bf(f0.y); pk.u[2]=f2bf(f0.z); pk.u[3]=f2bf(f0.w);
      pk.u[4]=f2bf(f1.x); pk.u[5]=f2bf(f1.y); pk.u[6]=f2bf(f1.z); pk.u[7]=f2bf(f1.w);
      *(short8_t*)(awbase + (2 * s + slab0) * 2048) = pk.v;
    }
  }
  // row norms: 8 consecutive tids share a row
  sq += __shfl_xor(sq, 1, 64);
  sq += __shfl_xor(sq, 2, 64);
  sq += __shfl_xor(sq, 4, 64);
  if (jc == 0) xsq_lds[ar] = sq;

  // ---- B staging geometry (swizzle folded into source pointer) ----
  const int tr = tid >> 2;                              // lB row 0..63 (+i*64)
  const int cB = (tid & 3) ^ ((tid >> 3) & 3);          // global chunk at this slot
  const u16* bsrc0 = cb + (size_t)tr * D_DIM + cB * 8;

  f32x4 acc[2][4];
  #pragma unroll
  for (int i = 0; i < 2; ++i)
    #pragma unroll
    for (int j = 0; j < 4; ++j)
      acc[i][j] = (f32x4){0.f, 0.f, 0.f, 0.f};

  __syncthreads();   // lA / csq / xsq ready

  const int fsw = (quad ^ ((l16 >> 1) & 3)) * 16;       // swizzled frag slot offset

  // ---- main loop: LDS + L2 only; 2 barriers/iter, drain is ~L2 latency ----
  #pragma unroll 1
  for (int k16 = 0; k16 < NITER; ++k16) {
    const int kk = k16 * 32;
    #pragma unroll
    for (int i = 0; i < 4; ++i)
      __builtin_amdgcn_global_load_lds(
          (const __attribute__((address_space(1))) void*)(bsrc0 + i * (64 * D_DIM) + kk),
          (__attribute__((address_space(3))) void*)(lB + (i * 256 + tid) * 16),
          16, 0, 0);
    __syncthreads();   // B(k) landed

    short8_t aF[2], bF[4];
    #pragma unroll
    for (int mi = 0; mi < 2; ++mi)
      aF[mi] = *(const short8_t*)(lA + k16 * 2048 + (mi * 16 + l16) * 64 + fsw);
    #pragma unroll
    for (int ni = 0; ni < 4; ++ni)
      bF[ni] = *(const short8_t*)(lB + (w * 64 + ni * 16 + l16) * 64 + fsw);
    #pragma unroll
    for (int ni = 0; ni < 4; ++ni)
      #pragma unroll
      for (int mi = 0; mi < 2; ++mi)
        acc[mi][ni] = __builtin_amdgcn_mfma_f32_16x16x32_bf16(
            aF[mi], bF[ni], acc[mi][ni], 0, 0, 0);

    if (k16 < NITER - 1) __syncthreads();   // all waves done reading lB
  }

  // ---- epilogue: Student-t + per-row partial sums ----
  float cs[4];
  #pragma unroll
  for (int ni = 0; ni < 4; ++ni) cs[ni] = csq_lds[w * 64 + ni * 16 + l16];

  #pragma unroll
  for (int mi = 0; mi < 2; ++mi) {
    #pragma unroll
    for (int v = 0; v < 4; ++v) {
      const int row = mi * 16 + quad * 4 + v;
      const float xs = xsq_lds[row];
      float s = 0.f;
      #pragma unroll
      for (int ni = 0; ni < 4; ++ni) {
        float d = xs + cs[ni] - 2.0f * acc[mi][ni][v];
        d = fmaxf(d, 0.f);
        float q = 1.0f / (1.0f + d);   // alpha=1: (1+d^2)^-1
        acc[mi][ni][v] = q;
        s += q;
      }
      s += __shfl_xor(s, 1, 64);
      s += __shfl_xor(s, 2, 64);
      s += __shfl_xor(s, 4, 64);
      s += __shfl_xor(s, 8, 64);
      if (l16 == 0) rowsum[w * BM + row] = s;
    }
  }
  __syncthreads();

  // ---- normalize + non-temporal store ----
  #pragma unroll
  for (int mi = 0; mi < 2; ++mi) {
    #pragma unroll
    for (int v = 0; v < 4; ++v) {
      const int row = mi * 16 + quad * 4 + v;
      const float tot = rowsum[row] + rowsum[BM + row]
                      + rowsum[2 * BM + row] + rowsum[3 * BM + row];
      const float inv = 1.0f / tot;
      float* orow = out + (size_t)(row0 + row) * K_CL;
      #pragma unroll
      for (int ni = 0; ni < 4; ++ni)
        __builtin_nontemporal_store(acc[mi][ni][v] * inv,
                                    orow + w * 64 + ni * 16 + l16);
    }
  }
}

extern "C" void kernel_launch(void* const* d_in, const int* in_sizes, int n_in,
                              void* d_out, int out_size, void* d_ws, size_t ws_size,
                              hipStream_t stream) {
  const float* x        = (const float*)d_in[0];
  const float* clusters = (const float*)d_in[1];
  float* out = (float*)d_out;
  const int N = in_sizes[0] / D_DIM;   // 65536

  u16*   cb  = (u16*)d_ws;                                   // 256 KB
  float* csq = (float*)((char*)d_ws + (size_t)K_CL * D_DIM * sizeof(u16));

  prep_kernel<<<K_CL, 128, 0, stream>>>(clusters, cb, csq);
  cluster_kernel<<<N / BM, 256, 0, stream>>>(x, cb, csq, out);
}